// Round 13
// baseline (90.644 us; speedup 1.0000x reference)
//
#include <hip/hip_runtime.h>

#define B_ 4
#define C_ 128
#define H_ 128
#define W_ 256
#define HW_ (H_ * W_)
#define ND 81
#define TH 4          // output rows per block
#define TW 16         // output cols per block
#define HR2 12        // f2 halo rows (TH + 8)
#define KC 32         // channels per chunk (= MFMA K)
#define NCHUNK (C_ / KC)
#define NTHREADS 512
#define F1OFF (HR2 * 32 * 64)      // 24576 B: f2 region = 384 px * 64 B
#define BUFSZ (F1OFF + 64 * 64)    // + f1 64 px * 64 B = 28672 B

typedef short bf16x8 __attribute__((ext_vector_type(8)));
typedef float f32x4 __attribute__((ext_vector_type(4)));
typedef unsigned int u32x4 __attribute__((ext_vector_type(4)));

// Pixel-major LDS (R11-verified): px block = 64 B (32ch bf16), 4 slots of 16B,
// slot' = slot ^ (px&3) ^ ((px>>2)&3). Bijective per block; even bank spread
// for both ds_write_b128 (lanes vary px) and MFMA ds_read_b128 (lanes vary
// col,quad). Row strides (32 px, 16 px) are multiples of 4 -> the XOR term
// depends only on col -> MFMA reads = ONE vaddr + imm offsets.
__device__ __forceinline__ int slotswz(int px, int slot) {
    return px * 64 + ((slot ^ (px & 3) ^ ((px >> 2) & 3)) * 16);
}

__device__ __forceinline__ unsigned int cvt_pk_bf16(float a, float b) {
    unsigned int r;
    asm("v_cvt_pk_bf16_f32 %0, %1, %2" : "=v"(r) : "v"(a), "v"(b));
    return r;
}

// ss += lo(u)^2 + hi(u)^2, one VOP3P instruction (R10-verified).
__device__ __forceinline__ void dot2_sq(unsigned int u, float& ss) {
    asm("v_dot2_f32_bf16 %0, %1, %1, %0" : "+v"(ss) : "v"(u));
}

// Barrier WITHOUT vmcnt drain (R6-verified): LDS ordered, globals in flight.
#define BARRIER()                                             \
    do {                                                      \
        asm volatile("s_waitcnt lgkmcnt(0)" ::: "memory");    \
        __builtin_amdgcn_s_barrier();                         \
    } while (0)

__global__ __launch_bounds__(NTHREADS)
void corr81_kernel(const float* __restrict__ f1g, const float* __restrict__ f2g,
                   float* __restrict__ out) {
    // Double-buffered: 2 x 28 KB = 56 KB -> 2 blocks/CU (112 KB).
    __shared__ __align__(16) char lds[2][BUFSZ];
    // invn arrays overlay buf0 (buf0 last read at k=2; invn written at k=3
    // after k=2's barrier; epilogue reads after k=3's barrier).
    float* invn2 = (float*)&lds[0][0];      // 384 floats (bytes 0..1536)
    float* invn1 = (float*)&lds[0][1536];   // 64 floats  (bytes 1536..1792)

    const int tid  = threadIdx.x;
    const int wave = tid >> 6;

    // XCD-aware block swizzle (T1). Bijective: 2048 = 8 * 256.
    const int flat = blockIdx.x + 16 * blockIdx.y + 512 * blockIdx.z;
    const int orig = (flat & 7) * 256 + (flat >> 3);
    const int w0 = (orig & 15) * TW;
    const int h0 = ((orig >> 4) & 31) * TH;
    const int b  = orig >> 9;
    const float* f2b = f2g + (size_t)b * C_ * HW_;
    const float* f1b = f1g + (size_t)b * C_ * HW_;

    if (wave < 4) {
        // ================= COMPUTE WAVES (0-3): MFMA + epilogue only =====
        const int lane = tid & 63;
        const int col  = lane & 15;
        const int quad = lane >> 4;
        const int w = wave;                       // output row within tile
        const int slotr = (quad ^ (col & 3) ^ ((col >> 2) & 3)) * 16;
        const int rb2 = w * 2048 + col * 64 + slotr;           // f2 frag base
        const int rb1 = F1OFF + (w * 16 + col) * 64 + slotr;   // f1 frag base

        f32x4 acc[9][2];
#pragma unroll
        for (int d = 0; d < 9; ++d) { acc[d][0] = (f32x4)0.f; acc[d][1] = (f32x4)0.f; }

        BARRIER();   // matches staging prologue barrier

#pragma unroll
        for (int k = 0; k < NCHUNK; ++k) {
            const char* base = &lds[k & 1][0];
            bf16x8 af = *(const bf16x8*)(base + rb1);
#pragma unroll
            for (int dy = 0; dy < 9; ++dy) {
                bf16x8 b0 = *(const bf16x8*)(base + rb2 + dy * 2048);
                bf16x8 b1 = *(const bf16x8*)(base + rb2 + dy * 2048 + 1024);
                acc[dy][0] = __builtin_amdgcn_mfma_f32_16x16x32_bf16(af, b0, acc[dy][0], 0, 0, 0);
                acc[dy][1] = __builtin_amdgcn_mfma_f32_16x16x32_bf16(af, b1, acc[dy][1], 0, 0, 0);
            }
            BARRIER();
        }

        // ---- epilogue (R10-verified band extraction) ----
        const int hOut = h0 + w;
        float* outB = out + (size_t)b * ND * HW_ + (size_t)hOut * W_;
        const float scale = 1.f / (float)C_;
#pragma unroll
        for (int dy = 0; dy < 9; ++dy) {
            int hr = w + dy;
#pragma unroll
            for (int t = 0; t < 2; ++t) {
                float i2 = invn2[hr * 32 + t * 16 + col];
#pragma unroll
                for (int r = 0; r < 4; ++r) {
                    int row = quad * 4 + r;
                    int dx = t * 16 + col - row;
                    if (dx >= 0 && dx <= 8) {
                        float v = acc[dy][t][r] * invn1[w * 16 + row] * i2 * scale;
                        v = (v >= 0.f) ? v : 0.1f * v;
                        outB[(size_t)(dy * 9 + dx) * HW_ + (w0 + row)] = v;
                    }
                }
            }
        }
    } else {
        // ================= STAGING WAVES (4-7): load + pack + norms ======
        const int st = tid - 256;
        const bool isf2 = st < 192;       // waves 4-6: f2 (2 px each); wave 7: f1
        // f2 pixels: pass A px = st (rows 0-5), pass B px = 192+st (rows 6-11)
        const int ww  = st & 31;
        const int hhA = st >> 5;
        const int gw  = w0 - 4 + ww;
        const bool okW = (gw >= 0) && (gw < W_);
        const int ghA = h0 - 4 + hhA, ghB = ghA + 6;
        const bool vA = isf2 && okW && (ghA >= 0) && (ghA < H_);
        const bool vB = isf2 && okW && (ghB >= 0) && (ghB < H_);
        const int offA = vA ? (ghA * W_ + gw) : 0;
        const int offB = vB ? (ghB * W_ + gw) : 0;
        const int pxA = st, pxB = 192 + st;
        // f1 pixel (wave 7): px1 = h*16 + wcol
        const int px1 = st - 192;
        const int off1 = (h0 + (px1 >> 4)) * W_ + (w0 + (px1 & 15));

        int waA[4], waB[4];
#pragma unroll
        for (int s = 0; s < 4; ++s) {
            waA[s] = isf2 ? slotswz(pxA, s) : (F1OFF + slotswz(px1, s));
            waB[s] = slotswz(pxB & 511, s);
        }

        f32x4 RA[8] = {}, RB[8] = {};
        float ssA = 0.f, ssB = 0.f;

#define S_ISSUE(kc0)                                                          \
        if (isf2) {                                                           \
            _Pragma("unroll")                                                 \
            for (int c = 0; c < 32; ++c) {                                    \
                RA[c >> 2][c & 3] = vA ? f2b[(size_t)((kc0) + c) * HW_ + offA] : 0.f; \
                RB[c >> 2][c & 3] = vB ? f2b[(size_t)((kc0) + c) * HW_ + offB] : 0.f; \
            }                                                                 \
        } else {                                                              \
            _Pragma("unroll")                                                 \
            for (int c = 0; c < 32; ++c)                                      \
                RA[c >> 2][c & 3] = f1b[(size_t)((kc0) + c) * HW_ + off1];    \
        }

#define S_PACK(buf)                                                           \
        {                                                                     \
            char* base = &lds[(buf)][0];                                      \
            _Pragma("unroll")                                                 \
            for (int s = 0; s < 4; ++s) {                                     \
                u32x4 U;                                                      \
                U[0] = cvt_pk_bf16(RA[s * 2][0], RA[s * 2][1]);               \
                U[1] = cvt_pk_bf16(RA[s * 2][2], RA[s * 2][3]);               \
                U[2] = cvt_pk_bf16(RA[s * 2 + 1][0], RA[s * 2 + 1][1]);       \
                U[3] = cvt_pk_bf16(RA[s * 2 + 1][2], RA[s * 2 + 1][3]);       \
                dot2_sq(U[0], ssA); dot2_sq(U[1], ssA);                       \
                dot2_sq(U[2], ssA); dot2_sq(U[3], ssA);                       \
                *(u32x4*)(base + waA[s]) = U;                                 \
            }                                                                 \
            if (isf2) {                                                       \
                _Pragma("unroll")                                             \
                for (int s = 0; s < 4; ++s) {                                 \
                    u32x4 U;                                                  \
                    U[0] = cvt_pk_bf16(RB[s * 2][0], RB[s * 2][1]);           \
                    U[1] = cvt_pk_bf16(RB[s * 2][2], RB[s * 2][3]);           \
                    U[2] = cvt_pk_bf16(RB[s * 2 + 1][0], RB[s * 2 + 1][1]);   \
                    U[3] = cvt_pk_bf16(RB[s * 2 + 1][2], RB[s * 2 + 1][3]);   \
                    dot2_sq(U[0], ssB); dot2_sq(U[1], ssB);                   \
                    dot2_sq(U[2], ssB); dot2_sq(U[3], ssB);                   \
                    *(u32x4*)(base + waB[s]) = U;                             \
                }                                                             \
            }                                                                 \
        }

        // prologue: stage chunk 0 -> buf0, issue chunk 1
        S_ISSUE(0);
        S_PACK(0);
        S_ISSUE(KC);
        BARRIER();

#pragma unroll
        for (int k = 0; k < NCHUNK; ++k) {
            if (k < NCHUNK - 1) {
                S_PACK((k + 1) & 1);                 // pack chunk k+1 (regs from last interval)
                if (k < NCHUNK - 2) S_ISSUE((k + 2) * KC);
            } else {
                // all channels accumulated: publish inverse norms
                float iA = 1.f / fmaxf(sqrtf(ssA), 1e-12f);
                if (isf2) {
                    invn2[pxA] = iA;
                    invn2[pxB] = 1.f / fmaxf(sqrtf(ssB), 1e-12f);
                } else {
                    invn1[px1] = iA;
                }
            }
            BARRIER();
        }
#undef S_ISSUE
#undef S_PACK
    }
}

extern "C" void kernel_launch(void* const* d_in, const int* in_sizes, int n_in,
                              void* d_out, int out_size, void* d_ws, size_t ws_size,
                              hipStream_t stream) {
    const float* f1 = (const float*)d_in[0];
    const float* f2 = (const float*)d_in[1];
    float* out = (float*)d_out;
    dim3 grid(W_ / TW, H_ / TH, B_);   // 16 x 32 x 4 = 2048 blocks
    corr81_kernel<<<grid, NTHREADS, 0, stream>>>(f1, f2, out);
}

// Round 14
// 64.579 us; speedup vs baseline: 1.4036x; 1.4036x over previous
//
#include <hip/hip_runtime.h>

#define B_ 4
#define C_ 128
#define H_ 128
#define W_ 256
#define HW_ (H_ * W_)
#define ND 81
#define TH 8          // output rows per block
#define TW 16         // output cols per block
#define HR 16         // f2 halo rows  (TH + 8)
#define WCOL 32       // f2 halo cols
#define KC 32         // channels per LDS chunk (= MFMA K)
#define NCHUNK (C_ / KC)
#define NTHREADS 512

typedef short bf16x8 __attribute__((ext_vector_type(8)));
typedef float f32x4 __attribute__((ext_vector_type(4)));
typedef float f32x4v __attribute__((ext_vector_type(4)));
typedef unsigned int u32x4 __attribute__((ext_vector_type(4)));

// Swizzle (HW-verified R1/R3-R12): XOR bits 4..6 of the full byte address by
// (r & 7) << 4 where r = px>>1 lives in bits >=7. Bijective.
// KEY linearity property exploited this round: for the MFMA fragment reads,
// pb = (wave+dy)*32 + col (+16): dy steps r by 16 and +16px steps r by 8 —
// both leave (r & 7) unchanged -> the XOR term is dy/t-invariant ->
// addr(dy,t) = addr(0,0) + dy*2048 + t*1024 (compile-time ds imm offsets).
__device__ __forceinline__ int swz(int px, int byteInHalf) {
    int r = px >> 1;
    int base = (r << 7) + ((px & 1) << 6) + byteInHalf;
    return base ^ ((r & 7) << 4);
}

// Native packed fp32->bf16 convert (gfx950). A/B use the same packing so the
// MFMA dot is invariant to lo/hi order.
__device__ __forceinline__ unsigned int cvt_pk_bf16(float a, float b) {
    unsigned int r;
    asm("v_cvt_pk_bf16_f32 %0, %1, %2" : "=v"(r) : "v"(a), "v"(b));
    return r;
}

// ss += lo(u)^2 + hi(u)^2, one VOP3P instruction (R10-verified).
__device__ __forceinline__ void dot2_sq(unsigned int u, float& ss) {
    asm("v_dot2_f32_bf16 %0, %1, %1, %0" : "+v"(ss) : "v"(u));
}

// Barrier WITHOUT vmcnt drain (R6-verified): LDS ordered, globals in flight.
#define BARRIER()                                             \
    do {                                                      \
        asm volatile("s_waitcnt lgkmcnt(0)" ::: "memory");    \
        __builtin_amdgcn_s_barrier();                         \
    } while (0)

__global__ __launch_bounds__(NTHREADS)
void corr81_kernel(const float* __restrict__ f1g, const float* __restrict__ f2g,
                   float* __restrict__ out) {
    // Double-buffered staging: exactly 80 KB -> 2 blocks/CU.
    __shared__ __align__(16) unsigned short f2s[2][HR * WCOL * KC];  // 2 x 32 KB
    __shared__ __align__(16) unsigned short f1s[2][TH * TW * KC];    // 2 x 8 KB
    // invn arrays overlay buf0 (hazard-free; epilogue reads post-barrier).
    float* invn2 = (float*)&f2s[0][0];   // 512 floats
    float* invn1 = (float*)&f1s[0][0];   // 128 floats

    const int tid  = threadIdx.x;
    const int lane = tid & 63;
    const int wave = tid >> 6;            // 0..7 -> output row within tile
    const int col  = lane & 15;
    const int quad = lane >> 4;

    // XCD-aware block swizzle (T1, verified R4). Bijective: 1024 = 8*128.
    const int flat = blockIdx.x + 16 * blockIdx.y + 256 * blockIdx.z;
    const int orig = (flat & 7) * 128 + (flat >> 3);
    const int w0 = (orig & 15) * TW;
    const int h0 = ((orig >> 4) & 15) * TH;
    const int b  = orig >> 8;
    const size_t inBase = (size_t)b * C_ * HW_;
    const float* f2base = f2g + inBase;
    const float* f1base = f1g + inBase;

    // f2 staging: (i 0..3) x per-thread (g2, cp2, rq)
    const int g2  = tid & 7;
    const int cp2 = (tid >> 3) & 15;
    const int rq  = tid >> 7;
    const int gw2 = w0 - 4 + g2 * 4;
    const bool colok2 = (gw2 >= 0) && (gw2 < W_);

    // f1 staging: one float4-pair per thread
    const int g1  = tid & 3;
    const int cp1 = (tid >> 2) & 15;
    const int r1  = tid >> 6;

    // ---- precomputed chunk-invariant 32-bit element offsets (R14 change):
    // global addr = uniform SGPR base (advances by KC*HW per chunk on SALU)
    // + these per-thread ints -> no per-chunk 64-bit VALU address chains.
    bool vrow[4];
    int off2[4];
#pragma unroll
    for (int i = 0; i < 4; ++i) {
        int r  = i * 4 + rq;
        int gh = h0 - 4 + r;
        vrow[i] = colok2 && (gh >= 0) && (gh < H_);
        off2[i] = cp2 * 2 * HW_ + (vrow[i] ? (gh * W_ + gw2) : 0);
    }
    const int off1 = cp1 * 2 * HW_ + (h0 + r1) * W_ + (w0 + g1 * 4);

    // ---- MFMA fragment base addresses (single vaddr + imm offsets) ----
    const int rb2 = swz(wave * 32 + col, quad * 16);              // dy=0,t=0
    const int rb1 = swz(wave * 16 + col, quad * 16);
    const char* f2c = (const char*)&f2s[0][0];
    const char* f1c = (const char*)&f1s[0][0];

    f32x4 acc[9][2];
#pragma unroll
    for (int d = 0; d < 9; ++d) {
        acc[d][0] = (f32x4)0.f;
        acc[d][1] = (f32x4)0.f;
    }

    float ss2 = 0.f, ss1 = 0.f;
    // prefetch regs: zero ONCE; invalid lanes never overwritten after.
    f32x4v A0[4] = {}, A1[4] = {}, B0, B1;

#define ISSUE_LOADS(kc0)                                                        \
    {                                                                           \
        const float* bk2 = f2base + (size_t)(kc0) * HW_;                        \
        const float* bk1 = f1base + (size_t)(kc0) * HW_;                        \
        _Pragma("unroll")                                                       \
        for (int i = 0; i < 4; ++i) {                                           \
            if (vrow[i]) {                                                      \
                A0[i] = *(const f32x4v*)(bk2 + off2[i]);                        \
                A1[i] = *(const f32x4v*)(bk2 + off2[i] + HW_);                  \
            }                                                                   \
        }                                                                       \
        B0 = *(const f32x4v*)(bk1 + off1);                                      \
        B1 = *(const f32x4v*)(bk1 + off1 + HW_);                                \
    }

#define PACK_WRITE(buf)                                                         \
    {                                                                           \
        char* w2 = (char*)&f2s[(buf)][0];                                       \
        char* w1 = (char*)&f1s[(buf)][0];                                       \
        _Pragma("unroll")                                                       \
        for (int i = 0; i < 4; ++i) {                                           \
            int r = i * 4 + rq;                                                 \
            _Pragma("unroll")                                                   \
            for (int j = 0; j < 4; ++j) {                                       \
                int px = r * 32 + g2 * 4 + j;                                   \
                *(unsigned int*)(w2 + swz(px, cp2 * 4)) =                       \
                    cvt_pk_bf16(A0[i][j], A1[i][j]);                            \
            }                                                                   \
        }                                                                       \
        _Pragma("unroll")                                                       \
        for (int j = 0; j < 4; ++j) {                                           \
            int px = r1 * 16 + g1 * 4 + j;                                      \
            *(unsigned int*)(w1 + swz(px, cp1 * 4)) = cvt_pk_bf16(B0[j], B1[j]);\
        }                                                                       \
    }

    // MFMA phase: one vaddr per operand stream; dy/t/buf all immediate.
#define MFMA_PHASE(buf)                                                         \
    {                                                                           \
        bf16x8 af = *(const bf16x8*)(f1c + rb1 + (buf) * 8192);                 \
        _Pragma("unroll")                                                       \
        for (int dy = 0; dy < 9; ++dy) {                                        \
            bf16x8 b0 = *(const bf16x8*)(f2c + rb2 + (buf) * 32768 + dy * 2048);\
            bf16x8 b1 = *(const bf16x8*)(f2c + rb2 + (buf) * 32768 + dy * 2048 + 1024); \
            acc[dy][0] = __builtin_amdgcn_mfma_f32_16x16x32_bf16(af, b0, acc[dy][0], 0, 0, 0); \
            acc[dy][1] = __builtin_amdgcn_mfma_f32_16x16x32_bf16(af, b1, acc[dy][1], 0, 0, 0); \
        }                                                                       \
    }

#define NORM_PHASE(buf)                                                         \
    {                                                                           \
        const char* r2 = (const char*)&f2s[(buf)][0];                           \
        const char* r1p = (const char*)&f1s[(buf)][0];                          \
        _Pragma("unroll")                                                       \
        for (int j = 0; j < 4; ++j) {                                           \
            u32x4 v = *(const u32x4*)(r2 + swz(tid, j * 16));                   \
            dot2_sq(v[0], ss2); dot2_sq(v[1], ss2);                             \
            dot2_sq(v[2], ss2); dot2_sq(v[3], ss2);                             \
        }                                                                       \
        u32x4 v = *(const u32x4*)(r1p + swz(tid >> 2, (tid & 3) * 16));         \
        dot2_sq(v[0], ss1); dot2_sq(v[1], ss1);                                 \
        dot2_sq(v[2], ss1); dot2_sq(v[3], ss1);                                 \
    }

    // ---- prologue: stage chunk 0 into buf0, issue chunk-1 loads ----
    ISSUE_LOADS(0);
    PACK_WRITE(0);
    ISSUE_LOADS(KC);
    BARRIER();

    // ---- main: one barrier per chunk (R10-verified structure) ----
#pragma unroll
    for (int k = 0; k < NCHUNK; ++k) {
        const int bk = k & 1;
        MFMA_PHASE(bk);
        if (k < NCHUNK - 1) {
            PACK_WRITE(bk ^ 1);
            if (k < NCHUNK - 2) ISSUE_LOADS((k + 2) * KC);
            NORM_PHASE(bk);
        } else {
            NORM_PHASE(bk);
            invn2[tid] = 1.f / fmaxf(sqrtf(ss2), 1e-12f);
            float t1 = ss1 + __shfl_xor(ss1, 1);
            t1 += __shfl_xor(t1, 2);
            if ((tid & 3) == 0) invn1[tid >> 2] = 1.f / fmaxf(sqrtf(t1), 1e-12f);
        }
        BARRIER();
    }

    // ---- epilogue: extract band, rescale, leaky-relu, store ----
    const int hOut = h0 + wave;
    float* outB = out + (size_t)b * ND * HW_ + (size_t)hOut * W_;
    const float scale = 1.f / (float)C_;

#pragma unroll
    for (int dy = 0; dy < 9; ++dy) {
        int hr = wave + dy;
#pragma unroll
        for (int t = 0; t < 2; ++t) {
            float i2 = invn2[hr * WCOL + t * 16 + col];
#pragma unroll
            for (int r = 0; r < 4; ++r) {
                int row = quad * 4 + r;
                int dx = t * 16 + col - row;
                if (dx >= 0 && dx <= 8) {
                    float v = acc[dy][t][r] * invn1[wave * 16 + row] * i2 * scale;
                    v = (v >= 0.f) ? v : 0.1f * v;
                    outB[(size_t)(dy * 9 + dx) * HW_ + (w0 + row)] = v;
                }
            }
        }
    }
#undef ISSUE_LOADS
#undef PACK_WRITE
#undef MFMA_PHASE
#undef NORM_PHASE
}

extern "C" void kernel_launch(void* const* d_in, const int* in_sizes, int n_in,
                              void* d_out, int out_size, void* d_ws, size_t ws_size,
                              hipStream_t stream) {
    const float* f1 = (const float*)d_in[0];
    const float* f2 = (const float*)d_in[1];
    float* out = (float*)d_out;
    dim3 grid(W_ / TW, H_ / TH, B_);   // 16 x 16 x 4 = 1024 blocks
    corr81_kernel<<<grid, NTHREADS, 0, stream>>>(f1, f2, out);
}